// Round 15
// baseline (57.124 us; speedup 1.0000x reference)
//
#include <hip/hip_runtime.h>

// LocallyConnectedGC: out[bt, m] = sum_n x[bt, n] * (S*W)[n, m] + b[m]
// S = band mask, half-width 4, ring of 208 -> 9 weights per output column.
//
// R14 = R12 structure with sBand ELIMINATED.
//  R12/R13: compiler rematerialized band LDS reads into the tile loop
//  (VGPR pinned at 36, 12 ds_read_b128/thread/tile, LDS pipe ~80% of
//  cycles; asm laundering was a no-op). Fix: there is no LDS band copy
//  anymore — each thread builds its 9 band float4s from GLOBAL W/S
//  (24 L2-hot float4 loads, R5's verified code, stays in VGPRs).
//  Steady state: 3 ds_read_b128/thread/tile (x only) + 36 FMA + nt store.
//  - Block = 832 threads (13 waves) stages one 16x208 x-tile/step via
//    global_load_lds (zero-VGPR prefetch), double-buffered, counted
//    vmcnt(1) + raw s_barrier (NO __syncthreads in loop).

#define NN   208
#define NC   52          // NN/4 float4 chunks per row
#define HW   4
#define BAND 9
#define TR   16          // rows per tile
#define THREADS 832      // = TR*NC threads: 13 waves
#define NBLK 512
#define TILE_F  (TR * NN)     // 3328 floats per tile

typedef float vfloat4 __attribute__((ext_vector_type(4)));

__global__ __launch_bounds__(THREADS) void lcgc_kernel(
    const float* __restrict__ x,
    const float* __restrict__ W,
    const float* __restrict__ b,
    const float* __restrict__ S,
    float* __restrict__ out,
    int total_rows)
{
    __shared__ float sX[2][TILE_F];      // 26.6 KB double-buffered x tile

    const int tid  = threadIdx.x;
    const int c    = tid % NC;           // fixed column chunk
    const int rg   = tid / NC;           // row within tile, 0..15
    const int wave = tid >> 6;

    // ---- Per-thread band from GLOBAL W/S (no LDS copy exists) ----
    // Needs (S*W)[n][m] for n = 4c-4 .. 4c+7 (12 rows, 4 cols each).
    float4 w4[BAND + 3], s4[BAND + 3];
    #pragma unroll
    for (int r = 0; r < BAND + 3; ++r) {
        int n = 4 * c - HW + r;
        if (n < 0) n += NN;
        else if (n >= NN) n -= NN;
        w4[r] = *reinterpret_cast<const float4*>(&W[n * NN + c * 4]);
        s4[r] = *reinterpret_cast<const float4*>(&S[n * NN + c * 4]);
    }
    float4 bnd[BAND];
    #pragma unroll
    for (int d = 0; d < BAND; ++d) {
        bnd[d].x = w4[d + 0].x * s4[d + 0].x;   // m=4c+0: n-row = d+0
        bnd[d].y = w4[d + 1].y * s4[d + 1].y;   // m=4c+1: n-row = d+1
        bnd[d].z = w4[d + 2].z * s4[d + 2].z;   // m=4c+2: n-row = d+2
        bnd[d].w = w4[d + 3].w * s4[d + 3].w;   // m=4c+3: n-row = d+3
    }
    const float4 bias4 = *reinterpret_cast<const float4*>(&b[c * 4]);

    const int cm = (c == 0)      ? NC - 1 : c - 1;
    const int cp = (c == NC - 1) ? 0      : c + 1;

    const long long ntiles_total = total_rows / TR;          // 8192
    const long long nt = ntiles_total / gridDim.x;           // 16 (runtime)
    const long long t0 = (long long)blockIdx.x * nt;

    // Wave-uniform LDS bases for staging (HW writes base + lane*16).
    float* const ldst0 = &sX[0][wave * 256];   // wave*64 float4 = wave*256 floats
    float* const ldst1 = &sX[1][wave * 256];

    #define STAGE(kt, bi)                                                     \
        do {                                                                  \
            const float* gsrc = x + (t0 + (kt)) * TILE_F + (long long)tid * 4;\
            __builtin_amdgcn_global_load_lds(                                 \
                (const __attribute__((address_space(1))) void*)(gsrc),        \
                (__attribute__((address_space(3))) void*)((bi) ? ldst1 : ldst0),\
                16, 0, 0);                                                    \
        } while (0)

    #define COMPUTE(kt, bi)                                                   \
        do {                                                                  \
            const float4* xr4 =                                               \
                reinterpret_cast<const float4*>(&sX[(bi)][rg * NN]);          \
            const float4 a = xr4[cm];                                         \
            const float4 m4 = xr4[c];                                         \
            const float4 e = xr4[cp];                                         \
            const float xv[12] = {a.x, a.y, a.z, a.w,                         \
                                  m4.x, m4.y, m4.z, m4.w,                     \
                                  e.x, e.y, e.z, e.w};                        \
            float4 acc = bias4;                                               \
            _Pragma("unroll")                                                 \
            for (int d = 0; d < BAND; ++d) {                                  \
                acc.x = fmaf(bnd[d].x, xv[0 + d], acc.x);                     \
                acc.y = fmaf(bnd[d].y, xv[1 + d], acc.y);                     \
                acc.z = fmaf(bnd[d].z, xv[2 + d], acc.z);                     \
                acc.w = fmaf(bnd[d].w, xv[3 + d], acc.w);                     \
            }                                                                 \
            vfloat4 av = {acc.x, acc.y, acc.z, acc.w};                        \
            __builtin_nontemporal_store(av, reinterpret_cast<vfloat4*>(       \
                out + (t0 + (kt)) * TILE_F + rg * NN + c * 4));               \
        } while (0)

    // Prologue: stage tile 0 into buffer 0. (Band global loads issued above
    // are older VMEM ops; vmcnt(1) below waits them out along with tile 0.)
    STAGE(0, 0);

    for (long long k = 0; k < nt - 1; ++k) {
        STAGE(k + 1, (int)((k + 1) & 1));
        // Wait for tile k's loads; leaves tile k+1's staging in flight.
        asm volatile("s_waitcnt vmcnt(1)" ::: "memory");
        __builtin_amdgcn_sched_barrier(0);
        __builtin_amdgcn_s_barrier();      // all waves' tile-k data visible
        COMPUTE(k, (int)(k & 1));
        asm volatile("" ::: "memory");
        __builtin_amdgcn_s_barrier();      // everyone done reading buf k&1
    }
    // Epilogue: last tile, nothing left to prefetch.
    asm volatile("s_waitcnt vmcnt(0)" ::: "memory");
    __builtin_amdgcn_sched_barrier(0);
    __builtin_amdgcn_s_barrier();
    COMPUTE(nt - 1, (int)((nt - 1) & 1));

    #undef STAGE
    #undef COMPUTE
}

extern "C" void kernel_launch(void* const* d_in, const int* in_sizes, int n_in,
                              void* d_out, int out_size, void* d_ws, size_t ws_size,
                              hipStream_t stream) {
    const float* x = (const float*)d_in[0];
    const float* W = (const float*)d_in[1];
    const float* b = (const float*)d_in[2];
    const float* S = (const float*)d_in[3];
    float* out = (float*)d_out;

    const int total_rows = in_sizes[0] / NN;   // 131072 = 8192 tiles of 16
    lcgc_kernel<<<dim3(NBLK), dim3(THREADS), 0, stream>>>(
        x, W, b, S, out, total_rows);
}

// Round 16
// 56.996 us; speedup vs baseline: 1.0022x; 1.0022x over previous
//
#include <hip/hip_runtime.h>

// LocallyConnectedGC: out[bt, m] = sum_n x[bt, n] * (S*W)[n, m] + b[m]
// S = band mask, half-width 4, ring of 208 -> 9 weights per output column.
//
// R14 = R12 structure with sBand ELIMINATED.
//  R12/R13: compiler rematerialized band LDS reads into the tile loop
//  (VGPR pinned at 36, 12 ds_read_b128/thread/tile, LDS pipe ~80% of
//  cycles; asm laundering was a no-op). Fix: there is no LDS band copy
//  anymore — each thread builds its 9 band float4s from GLOBAL W/S
//  (24 L2-hot float4 loads, R5's verified code, stays in VGPRs).
//  Steady state: 3 ds_read_b128/thread/tile (x only) + 36 FMA + nt store.
//  - Block = 832 threads (13 waves) stages one 16x208 x-tile/step via
//    global_load_lds (zero-VGPR prefetch), double-buffered, counted
//    vmcnt(1) + raw s_barrier (NO __syncthreads in loop).

#define NN   208
#define NC   52          // NN/4 float4 chunks per row
#define HW   4
#define BAND 9
#define TR   16          // rows per tile
#define THREADS 832      // = TR*NC threads: 13 waves
#define NBLK 512
#define TILE_F  (TR * NN)     // 3328 floats per tile

typedef float vfloat4 __attribute__((ext_vector_type(4)));

__global__ __launch_bounds__(THREADS) void lcgc_kernel(
    const float* __restrict__ x,
    const float* __restrict__ W,
    const float* __restrict__ b,
    const float* __restrict__ S,
    float* __restrict__ out,
    int total_rows)
{
    __shared__ float sX[2][TILE_F];      // 26.6 KB double-buffered x tile

    const int tid  = threadIdx.x;
    const int c    = tid % NC;           // fixed column chunk
    const int rg   = tid / NC;           // row within tile, 0..15
    const int wave = tid >> 6;

    // ---- Per-thread band from GLOBAL W/S (no LDS copy exists) ----
    // Needs (S*W)[n][m] for n = 4c-4 .. 4c+7 (12 rows, 4 cols each).
    float4 w4[BAND + 3], s4[BAND + 3];
    #pragma unroll
    for (int r = 0; r < BAND + 3; ++r) {
        int n = 4 * c - HW + r;
        if (n < 0) n += NN;
        else if (n >= NN) n -= NN;
        w4[r] = *reinterpret_cast<const float4*>(&W[n * NN + c * 4]);
        s4[r] = *reinterpret_cast<const float4*>(&S[n * NN + c * 4]);
    }
    float4 bnd[BAND];
    #pragma unroll
    for (int d = 0; d < BAND; ++d) {
        bnd[d].x = w4[d + 0].x * s4[d + 0].x;   // m=4c+0: n-row = d+0
        bnd[d].y = w4[d + 1].y * s4[d + 1].y;   // m=4c+1: n-row = d+1
        bnd[d].z = w4[d + 2].z * s4[d + 2].z;   // m=4c+2: n-row = d+2
        bnd[d].w = w4[d + 3].w * s4[d + 3].w;   // m=4c+3: n-row = d+3
    }
    const float4 bias4 = *reinterpret_cast<const float4*>(&b[c * 4]);

    const int cm = (c == 0)      ? NC - 1 : c - 1;
    const int cp = (c == NC - 1) ? 0      : c + 1;

    const long long ntiles_total = total_rows / TR;          // 8192
    const long long nt = ntiles_total / gridDim.x;           // 16 (runtime)
    const long long t0 = (long long)blockIdx.x * nt;

    // Wave-uniform LDS bases for staging (HW writes base + lane*16).
    float* const ldst0 = &sX[0][wave * 256];   // wave*64 float4 = wave*256 floats
    float* const ldst1 = &sX[1][wave * 256];

    #define STAGE(kt, bi)                                                     \
        do {                                                                  \
            const float* gsrc = x + (t0 + (kt)) * TILE_F + (long long)tid * 4;\
            __builtin_amdgcn_global_load_lds(                                 \
                (const __attribute__((address_space(1))) void*)(gsrc),        \
                (__attribute__((address_space(3))) void*)((bi) ? ldst1 : ldst0),\
                16, 0, 0);                                                    \
        } while (0)

    #define COMPUTE(kt, bi)                                                   \
        do {                                                                  \
            const float4* xr4 =                                               \
                reinterpret_cast<const float4*>(&sX[(bi)][rg * NN]);          \
            const float4 a = xr4[cm];                                         \
            const float4 m4 = xr4[c];                                         \
            const float4 e = xr4[cp];                                         \
            const float xv[12] = {a.x, a.y, a.z, a.w,                         \
                                  m4.x, m4.y, m4.z, m4.w,                     \
                                  e.x, e.y, e.z, e.w};                        \
            float4 acc = bias4;                                               \
            _Pragma("unroll")                                                 \
            for (int d = 0; d < BAND; ++d) {                                  \
                acc.x = fmaf(bnd[d].x, xv[0 + d], acc.x);                     \
                acc.y = fmaf(bnd[d].y, xv[1 + d], acc.y);                     \
                acc.z = fmaf(bnd[d].z, xv[2 + d], acc.z);                     \
                acc.w = fmaf(bnd[d].w, xv[3 + d], acc.w);                     \
            }                                                                 \
            vfloat4 av = {acc.x, acc.y, acc.z, acc.w};                        \
            __builtin_nontemporal_store(av, reinterpret_cast<vfloat4*>(       \
                out + (t0 + (kt)) * TILE_F + rg * NN + c * 4));               \
        } while (0)

    // Prologue: stage tile 0 into buffer 0. (Band global loads issued above
    // are older VMEM ops; vmcnt(1) below waits them out along with tile 0.)
    STAGE(0, 0);

    for (long long k = 0; k < nt - 1; ++k) {
        STAGE(k + 1, (int)((k + 1) & 1));
        // Wait for tile k's loads; leaves tile k+1's staging in flight.
        asm volatile("s_waitcnt vmcnt(1)" ::: "memory");
        __builtin_amdgcn_sched_barrier(0);
        __builtin_amdgcn_s_barrier();      // all waves' tile-k data visible
        COMPUTE(k, (int)(k & 1));
        asm volatile("" ::: "memory");
        __builtin_amdgcn_s_barrier();      // everyone done reading buf k&1
    }
    // Epilogue: last tile, nothing left to prefetch.
    asm volatile("s_waitcnt vmcnt(0)" ::: "memory");
    __builtin_amdgcn_sched_barrier(0);
    __builtin_amdgcn_s_barrier();
    COMPUTE(nt - 1, (int)((nt - 1) & 1));

    #undef STAGE
    #undef COMPUTE
}

extern "C" void kernel_launch(void* const* d_in, const int* in_sizes, int n_in,
                              void* d_out, int out_size, void* d_ws, size_t ws_size,
                              hipStream_t stream) {
    const float* x = (const float*)d_in[0];
    const float* W = (const float*)d_in[1];
    const float* b = (const float*)d_in[2];
    const float* S = (const float*)d_in[3];
    float* out = (float*)d_out;

    const int total_rows = in_sizes[0] / NN;   // 131072 = 8192 tiles of 16
    lcgc_kernel<<<dim3(NBLK), dim3(THREADS), 0, stream>>>(
        x, W, b, S, out, total_rows);
}

// Round 18
// 51.663 us; speedup vs baseline: 1.1057x; 1.1032x over previous
//
#include <hip/hip_runtime.h>

// LocallyConnectedGC: out[bt, m] = sum_n x[bt, n] * (S*W)[n, m] + b[m]
// S = band mask, half-width 4, ring of 208 -> 9 weights per output column.
//
// R16 = R15 with the buffer race FIXED: prefetch distance 3, 4 buffers.
//  R15 staged tile k+4 into buffer (k+4)&3 == k&3 while COMPUTE(k) was
//  reading it -> corruption (absmax 2.14). With distance 3: iter k stages
//  k+3 into (k+3)&3, reads k&3; buffer k&3 is only re-staged at iter k+1
//  (tile k+4), AFTER the post-compute barrier orders all reads.
//  Counted vmcnt = #VMEM ops issued after stage k (in-order retirement):
//  nv = min(k,3) stores + min(nt-1-k,3) stages; steady state vmcnt(6),
//  so 3 tile-stages (~10KB/wave) stay in flight across barriers.
//  Band stays in LDS (R13/R14: compiler re-reads it from somewhere every
//  tile; LDS is the cheapest somewhere).

#define NN   208
#define NC   52          // NN/4 float4 chunks per row
#define HW   4
#define BAND 9
#define TR   16          // rows per tile
#define THREADS 832      // = TR*NC threads: 13 waves
#define NBLK 512
#define TILE_F  (TR * NN)     // 3328 floats per tile
#define DEPTH 4               // LDS buffers; prefetch distance = 3

typedef float vfloat4 __attribute__((ext_vector_type(4)));

__global__ __launch_bounds__(THREADS) void lcgc_kernel(
    const float* __restrict__ x,
    const float* __restrict__ W,
    const float* __restrict__ b,
    const float* __restrict__ S,
    float* __restrict__ out,
    int total_rows)
{
    __shared__ float sX[DEPTH][TILE_F];  // 53.2 KB 4-deep x tiles
    __shared__ float sBand[BAND * NN];   // 7.5 KB masked weight band

    const int tid = threadIdx.x;

    // One-time cooperative band build (coalesced over m; W/S L2-hot).
    for (int i = tid; i < BAND * NN; i += THREADS) {
        int d = i / NN;
        int m = i - d * NN;
        int n = m + d - HW;
        if (n < 0) n += NN;
        else if (n >= NN) n -= NN;
        sBand[i] = W[n * NN + m] * S[n * NN + m];
    }
    __syncthreads();   // before any staging: full drain here is fine

    const int c    = tid % NC;           // fixed column chunk
    const int rg   = tid / NC;           // row within tile, 0..15
    const int wave = tid >> 6;

    const float4 bias4 = *reinterpret_cast<const float4*>(&b[c * 4]);
    const int cm = (c == 0)      ? NC - 1 : c - 1;
    const int cp = (c == NC - 1) ? 0      : c + 1;

    const long long ntiles_total = total_rows / TR;          // 8192
    const long long nt = ntiles_total / gridDim.x;           // 16 (runtime)
    const long long t0 = (long long)blockIdx.x * nt;

    // Wave-uniform LDS staging base (HW writes base + lane*16).
    float* const ldsw = &sX[0][wave * 256];  // + buf*TILE_F selects buffer

    #define STAGE(kt)                                                         \
        do {                                                                  \
            const float* gsrc = x + (t0 + (kt)) * TILE_F + (long long)tid * 4;\
            float* ldst = ldsw + (int)((kt) & (DEPTH - 1)) * TILE_F;          \
            __builtin_amdgcn_global_load_lds(                                 \
                (const __attribute__((address_space(1))) void*)(gsrc),        \
                (__attribute__((address_space(3))) void*)(ldst),              \
                16, 0, 0);                                                    \
        } while (0)

    #define COMPUTE(kt)                                                       \
        do {                                                                  \
            const float4* xr4 = reinterpret_cast<const float4*>(              \
                &sX[(int)((kt) & (DEPTH - 1))][rg * NN]);                     \
            const float4 a = xr4[cm];                                         \
            const float4 m4 = xr4[c];                                         \
            const float4 e = xr4[cp];                                         \
            const float xv[12] = {a.x, a.y, a.z, a.w,                         \
                                  m4.x, m4.y, m4.z, m4.w,                     \
                                  e.x, e.y, e.z, e.w};                        \
            float4 acc = bias4;                                               \
            const float4* band4 = reinterpret_cast<const float4*>(sBand);     \
            _Pragma("unroll")                                                 \
            for (int d = 0; d < BAND; ++d) {                                  \
                const float4 bd = band4[d * NC + c];                          \
                acc.x = fmaf(bd.x, xv[0 + d], acc.x);                         \
                acc.y = fmaf(bd.y, xv[1 + d], acc.y);                         \
                acc.z = fmaf(bd.z, xv[2 + d], acc.z);                         \
                acc.w = fmaf(bd.w, xv[3 + d], acc.w);                         \
            }                                                                 \
            vfloat4 av = {acc.x, acc.y, acc.z, acc.w};                        \
            __builtin_nontemporal_store(av, reinterpret_cast<vfloat4*>(       \
                out + (t0 + (kt)) * TILE_F + rg * NN + c * 4));               \
        } while (0)

    // Prologue: stage tiles 0..2 (distance 3).
    STAGE(0); STAGE(1); STAGE(2);

    for (long long k = 0; k < nt; ++k) {
        if (k + 3 < nt) STAGE(k + 3);
        // Wait until stage k retired: exactly nv VMEM ops were issued
        // after it (min(k,3) nt-stores + min(nt-1-k,3) stages).
        {
            const int a1 = (int)(k < 3 ? k : 3);
            const int a2 = (int)((nt - 1 - k) < 3 ? (nt - 1 - k) : 3);
            switch (a1 + a2) {
            case 0: asm volatile("s_waitcnt vmcnt(0)" ::: "memory"); break;
            case 1: asm volatile("s_waitcnt vmcnt(1)" ::: "memory"); break;
            case 2: asm volatile("s_waitcnt vmcnt(2)" ::: "memory"); break;
            case 3: asm volatile("s_waitcnt vmcnt(3)" ::: "memory"); break;
            case 4: asm volatile("s_waitcnt vmcnt(4)" ::: "memory"); break;
            case 5: asm volatile("s_waitcnt vmcnt(5)" ::: "memory"); break;
            default: asm volatile("s_waitcnt vmcnt(6)" ::: "memory"); break;
            }
        }
        __builtin_amdgcn_sched_barrier(0);
        __builtin_amdgcn_s_barrier();      // all waves' tile-k data visible
        COMPUTE(k);
        asm volatile("" ::: "memory");
        __builtin_amdgcn_s_barrier();      // reads of buf k&3 done before
                                           // iter k+1 restages it (tile k+4)
    }

    #undef STAGE
    #undef COMPUTE
}

extern "C" void kernel_launch(void* const* d_in, const int* in_sizes, int n_in,
                              void* d_out, int out_size, void* d_ws, size_t ws_size,
                              hipStream_t stream) {
    const float* x = (const float*)d_in[0];
    const float* W = (const float*)d_in[1];
    const float* b = (const float*)d_in[2];
    const float* S = (const float*)d_in[3];
    float* out = (float*)d_out;

    const int total_rows = in_sizes[0] / NN;   // 131072 = 8192 tiles of 16
    lcgc_kernel<<<dim3(NBLK), dim3(THREADS), 0, stream>>>(
        x, W, b, S, out, total_rows);
}

// Round 19
// 45.241 us; speedup vs baseline: 1.2626x; 1.1419x over previous
//
#include <hip/hip_runtime.h>

// LocallyConnectedGC: out[bt, m] = sum_n x[bt, n] * (S*W)[n, m] + b[m]
// S = band mask, half-width 4, ring of 208 -> 9 weights per output column.
//
// R17 = R12 skeleton + band amortized over 2 rows/thread.
//  Evidence R11-R16: LDS pipe is the wall (12 ds_read_b128/thread/tile,
//  ~60K cyc + 26K conflict cyc of a ~100K budget; deeper prefetch in R16
//  made things worse, HBM latency is NOT the limiter). Band re-reads are
//  unavoidable (R12/R13/R14: compiler remats them), so amortize: tile=32
//  rows, thread computes rows rg and rg+16 -> 16 b128 per 2 rows (8/row).
//  - Bias moved to LDS: post-syncthreads VMEM queue = stages/stores ONLY,
//    making the counted vmcnt exact (R16 had a latent k=0 miscount).
//  - 2 LDS buffers, distance 1, vmcnt leaves stores + next stage in
//    flight: nv = 2*[k>=1] + 2*[k+1<nt]  (2 / 4 / ... / 4 / 2).

#define NN   208
#define NC   52          // NN/4 float4 chunks per row
#define HW   4
#define BAND 9
#define TR   32          // rows per tile
#define THREADS 832      // 13 waves; thread = (chunk c, row rg) x {0,+16}
#define NBLK 512
#define TILE_F  (TR * NN)     // 6656 floats per tile
#define TILE_F4 (TILE_F / 4)  // 1664 float4 = 2 per thread

typedef float vfloat4 __attribute__((ext_vector_type(4)));

__global__ __launch_bounds__(THREADS) void lcgc_kernel(
    const float* __restrict__ x,
    const float* __restrict__ W,
    const float* __restrict__ b,
    const float* __restrict__ S,
    float* __restrict__ out,
    int total_rows)
{
    __shared__ float sX[2][TILE_F];      // 53.2 KB double-buffered x tile
    __shared__ float sBand[BAND * NN];   // 7.5 KB masked weight band
    __shared__ float sBias[NN];

    const int tid = threadIdx.x;

    // One-time cooperative band+bias build (coalesced; W/S/b L2-hot).
    for (int i = tid; i < BAND * NN; i += THREADS) {
        int d = i / NN;
        int m = i - d * NN;
        int n = m + d - HW;
        if (n < 0) n += NN;
        else if (n >= NN) n -= NN;
        sBand[i] = W[n * NN + m] * S[n * NN + m];
    }
    if (tid < NN) sBias[tid] = b[tid];
    __syncthreads();   // drains ALL prior vmem: queue now stages/stores only

    const int c    = tid % NC;           // fixed column chunk
    const int rg   = tid / NC;           // row within tile, 0..15 (+16 pair)
    const int wave = tid >> 6;

    const int cm = (c == 0)      ? NC - 1 : c - 1;
    const int cp = (c == NC - 1) ? 0      : c + 1;

    const long long ntiles_total = total_rows / TR;          // 4096
    const long long nt = ntiles_total / gridDim.x;           // 8 (runtime)
    const long long t0 = (long long)blockIdx.x * nt;

    // Wave-uniform LDS staging bases (HW writes base + lane*16).
    // Thread stages float4 #tid and #(tid+832) of the 1664-float4 tile.
    float* const ldswA = &sX[0][wave * 256];          // float4 64w..64w+63
    float* const ldswB = &sX[0][3328 + wave * 256];   // float4 832+64w..

    #define STAGE(kt)                                                         \
        do {                                                                  \
            const long long base = (t0 + (kt)) * TILE_F;                      \
            const int bo = (int)((kt) & 1) * TILE_F;                          \
            __builtin_amdgcn_global_load_lds(                                 \
                (const __attribute__((address_space(1))) void*)               \
                    (x + base + (long long)tid * 4),                          \
                (__attribute__((address_space(3))) void*)(ldswA + bo),        \
                16, 0, 0);                                                    \
            __builtin_amdgcn_global_load_lds(                                 \
                (const __attribute__((address_space(1))) void*)               \
                    (x + base + 3328 + (long long)tid * 4),                   \
                (__attribute__((address_space(3))) void*)(ldswB + bo),        \
                16, 0, 0);                                                    \
        } while (0)

    #define ROWCOMP(xr4, acc)                                                 \
        do {                                                                  \
            const float4 a = (xr4)[cm];                                       \
            const float4 m4 = (xr4)[c];                                       \
            const float4 e = (xr4)[cp];                                       \
            const float xv[12] = {a.x, a.y, a.z, a.w,                         \
                                  m4.x, m4.y, m4.z, m4.w,                     \
                                  e.x, e.y, e.z, e.w};                        \
            _Pragma("unroll")                                                 \
            for (int d = 0; d < BAND; ++d) {                                  \
                const float4 bd = band4[d * NC + c];                          \
                acc.x = fmaf(bd.x, xv[0 + d], acc.x);                         \
                acc.y = fmaf(bd.y, xv[1 + d], acc.y);                         \
                acc.z = fmaf(bd.z, xv[2 + d], acc.z);                         \
                acc.w = fmaf(bd.w, xv[3 + d], acc.w);                         \
            }                                                                 \
        } while (0)

    #define COMPUTE(kt)                                                       \
        do {                                                                  \
            const int bi = (int)((kt) & 1);                                   \
            const float4* band4 = reinterpret_cast<const float4*>(sBand);     \
            const float4 bias4 =                                              \
                *reinterpret_cast<const float4*>(&sBias[c * 4]);              \
            const float4* xr4a =                                              \
                reinterpret_cast<const float4*>(&sX[bi][rg * NN]);            \
            const float4* xr4b =                                              \
                reinterpret_cast<const float4*>(&sX[bi][(rg + 16) * NN]);     \
            float4 acc0 = bias4;                                              \
            float4 acc1 = bias4;                                              \
            ROWCOMP(xr4a, acc0);                                              \
            ROWCOMP(xr4b, acc1);                                              \
            const long long grow = (t0 + (kt)) * TR + rg;                     \
            vfloat4 av0 = {acc0.x, acc0.y, acc0.z, acc0.w};                   \
            vfloat4 av1 = {acc1.x, acc1.y, acc1.z, acc1.w};                   \
            __builtin_nontemporal_store(av0, reinterpret_cast<vfloat4*>(      \
                out + grow * NN + c * 4));                                    \
            __builtin_nontemporal_store(av1, reinterpret_cast<vfloat4*>(      \
                out + (grow + 16) * NN + c * 4));                             \
        } while (0)

    // Prologue: stage tile 0 into buffer 0.
    STAGE(0);

    for (long long k = 0; k < nt; ++k) {
        if (k + 1 < nt) STAGE(k + 1);
        // Exact in-order count: queue = stage_k(2) [, stores_{k-1}(2)]
        // [, stage_{k+1}(2)]. Complete stage_k, leave the rest in flight.
        {
            const int nv = (k >= 1 ? 2 : 0) + (k + 1 < nt ? 2 : 0);
            switch (nv) {
            case 0: asm volatile("s_waitcnt vmcnt(0)" ::: "memory"); break;
            case 2: asm volatile("s_waitcnt vmcnt(2)" ::: "memory"); break;
            default: asm volatile("s_waitcnt vmcnt(4)" ::: "memory"); break;
            }
        }
        __builtin_amdgcn_sched_barrier(0);
        __builtin_amdgcn_s_barrier();      // all waves' tile-k data visible
        COMPUTE(k);
        asm volatile("" ::: "memory");
        __builtin_amdgcn_s_barrier();      // reads of buf k&1 done before
                                           // iter k+1 restages it
    }

    #undef STAGE
    #undef ROWCOMP
    #undef COMPUTE
}

extern "C" void kernel_launch(void* const* d_in, const int* in_sizes, int n_in,
                              void* d_out, int out_size, void* d_ws, size_t ws_size,
                              hipStream_t stream) {
    const float* x = (const float*)d_in[0];
    const float* W = (const float*)d_in[1];
    const float* b = (const float*)d_in[2];
    const float* S = (const float*)d_in[3];
    float* out = (float*)d_out;

    const int total_rows = in_sizes[0] / NN;   // 131072 = 4096 tiles of 32
    lcgc_kernel<<<dim3(NBLK), dim3(THREADS), 0, stream>>>(
        x, W, b, S, out, total_rows);
}